// Round 1
// baseline (833.492 us; speedup 1.0000x reference)
//
#include <hip/hip_runtime.h>
#include <math.h>

#define B_ 16
#define S_ 4096
#define H_ 1024
#define Q_ 1024
#define K_ 2048

__device__ __forceinline__ float fast_tanh(float x) {
    // tanh(x) = 1 - 2/(exp(2x)+1); exact at both saturations (exp->inf => 1, exp->0 => -1)
    float e = __expf(2.0f * x);
    float r = __builtin_amdgcn_rcpf(e + 1.0f);   // v_rcp_f32, ~1 ulp
    return 1.0f - 2.0f * r;
}

__device__ __forceinline__ float wave_reduce_sum(float v) {
#pragma unroll
    for (int off = 32; off > 0; off >>= 1)
        v += __shfl_xor(v, off, 64);
    return v;
}

// ---------------- kernel 1: q[b,h] = sum_q query[b,q] * Wq[h,q] ----------------
// one wave per (b,h); 16384 waves
__global__ __launch_bounds__(256) void qproj_kernel(const float* __restrict__ query,
                                                    const float* __restrict__ Wq,
                                                    float* __restrict__ qws) {
    int wave = (blockIdx.x * 256 + threadIdx.x) >> 6;
    int lane = threadIdx.x & 63;
    int b = wave >> 10;          // H_=1024
    int h = wave & 1023;
    const float4* wrow = (const float4*)(Wq + (size_t)h * Q_);
    const float4* qrow = (const float4*)(query + (size_t)b * Q_);
    float acc = 0.f;
#pragma unroll
    for (int m = 0; m < 4; ++m) {
        int i = m * 64 + lane;   // 256 float4 = 1024 floats
        float4 w = wrow[i];
        float4 q = qrow[i];
        acc += w.x * q.x + w.y * q.y + w.z * q.z + w.w * q.w;
    }
    acc = wave_reduce_sum(acc);
    if (lane == 0) qws[wave] = acc;   // wave == b*H_ + h
}

// ---------------- kernel 2: scores[b,s] = sum_h tanh(q[b,h]+pk[b,s,h]) * we[h] ----------------
// one wave per (b,s) row of 1024; 65536 waves, float4 loads (1 KB/instr/wave)
__global__ __launch_bounds__(256) void scores_kernel(const float* __restrict__ pk,
                                                     const float* __restrict__ qws,
                                                     const float* __restrict__ we,
                                                     float* __restrict__ scores) {
    int row  = (blockIdx.x * 256 + threadIdx.x) >> 6;  // b*S_ + s
    int lane = threadIdx.x & 63;
    int b = row >> 12;           // S_=4096
    const float4* prow = (const float4*)(pk + (size_t)row * H_);
    const float4* qrow = (const float4*)(qws + (size_t)b * H_);
    const float4* wrow = (const float4*)we;
    float acc = 0.f;
#pragma unroll
    for (int m = 0; m < 4; ++m) {
        int i = m * 64 + lane;
        float4 p = prow[i];
        float4 q = qrow[i];
        float4 w = wrow[i];
        acc += fast_tanh(q.x + p.x) * w.x;
        acc += fast_tanh(q.y + p.y) * w.y;
        acc += fast_tanh(q.z + p.z) * w.z;
        acc += fast_tanh(q.w + p.w) * w.w;
    }
    acc = wave_reduce_sum(acc);
    if (lane == 0) scores[row] = acc;
}

// ---------------- kernel 3: masked softmax over s; one block per b ----------------
__global__ __launch_bounds__(256) void softmax_kernel(const float* __restrict__ scores,
                                                      const int* __restrict__ mask,
                                                      float* __restrict__ alphas) {
    int b = blockIdx.x;
    int tid = threadIdx.x;
    __shared__ float red[8];
    float v[16];
    float lmax = -INFINITY;
#pragma unroll
    for (int m = 0; m < 16; ++m) {
        int s = m * 256 + tid;
        float sc = scores[b * S_ + s];
        int mk = mask[b * S_ + s];
        v[m] = mk ? sc : -INFINITY;
        lmax = fmaxf(lmax, v[m]);
    }
#pragma unroll
    for (int off = 32; off > 0; off >>= 1)
        lmax = fmaxf(lmax, __shfl_xor(lmax, off, 64));
    int wid = tid >> 6;
    if ((tid & 63) == 0) red[wid] = lmax;
    __syncthreads();
    float mx = fmaxf(fmaxf(red[0], red[1]), fmaxf(red[2], red[3]));
    float lsum = 0.f;
#pragma unroll
    for (int m = 0; m < 16; ++m) {
        float e = (v[m] == -INFINITY) ? 0.f : __expf(v[m] - mx);
        v[m] = e;
        lsum += e;
    }
    lsum = wave_reduce_sum(lsum);
    if ((tid & 63) == 0) red[4 + wid] = lsum;
    __syncthreads();
    float total = red[4] + red[5] + red[6] + red[7];
    float rinv = 1.0f / total;
#pragma unroll
    for (int m = 0; m < 16; ++m) {
        int s = m * 256 + tid;
        alphas[b * S_ + s] = v[m] * rinv;
    }
}

// ---------------- kernel 4: partial context over s-chunks ----------------
// grid (schunks, K_/1024, B_); block 256; each thread owns a float4 of k
__global__ __launch_bounds__(256) void context_partial_kernel(const float* __restrict__ value,
                                                              const float* __restrict__ alphas,
                                                              float* __restrict__ partial,
                                                              int schunks, int L) {
    extern __shared__ float la[];
    int c  = blockIdx.x;
    int kt = blockIdx.y;
    int b  = blockIdx.z;
    int tid = threadIdx.x;
    int s0 = c * L;
    for (int i = tid; i < L; i += 256) la[i] = alphas[b * S_ + s0 + i];
    __syncthreads();
    const float4* vp = (const float4*)(value + ((size_t)(b * S_ + s0)) * K_ + kt * 1024) + tid;
    float4 acc = make_float4(0.f, 0.f, 0.f, 0.f);
#pragma unroll 4
    for (int i = 0; i < L; ++i) {
        float a = la[i];
        float4 vv = vp[(size_t)i * (K_ / 4)];
        acc.x = fmaf(a, vv.x, acc.x);
        acc.y = fmaf(a, vv.y, acc.y);
        acc.z = fmaf(a, vv.z, acc.z);
        acc.w = fmaf(a, vv.w, acc.w);
    }
    float4* pout = (float4*)(partial + ((size_t)(b * schunks + c)) * K_ + kt * 1024) + tid;
    *pout = acc;
}

// ---------------- kernel 5: reduce partials into context ----------------
__global__ __launch_bounds__(256) void context_reduce_kernel(const float* __restrict__ partial,
                                                             float* __restrict__ ctx,
                                                             int schunks) {
    int idx = blockIdx.x * 256 + threadIdx.x;  // 0 .. B_*K_-1
    int b = idx >> 11;                         // K_=2048
    int k = idx & 2047;
    float acc = 0.f;
    for (int c = 0; c < schunks; ++c)
        acc += partial[((size_t)(b * schunks + c)) * K_ + k];
    ctx[idx] = acc;
}

extern "C" void kernel_launch(void* const* d_in, const int* in_sizes, int n_in,
                              void* d_out, int out_size, void* d_ws, size_t ws_size,
                              hipStream_t stream) {
    const int*   mask     = (const int*)d_in[0];
    const float* query    = (const float*)d_in[1];
    const float* proj_key = (const float*)d_in[2];
    const float* value    = (const float*)d_in[3];
    const float* Wq       = (const float*)d_in[4];
    const float* w_energy = (const float*)d_in[5];

    float* out    = (float*)d_out;
    float* ctx    = out;            // B*1*K = 32768 floats
    float* alphas = out + B_ * K_;  // B*1*S = 65536 floats

    float* ws      = (float*)d_ws;
    float* qws     = ws;                      // B*H = 16384 floats
    float* scores  = ws + B_ * H_;            // B*S = 65536 floats
    float* partial = ws + B_ * H_ + B_ * S_;  // schunks*B*K floats

    // pick s-chunk count that fits the workspace (ws_size constant per session)
    size_t avail = ws_size / 4;
    size_t head  = (size_t)B_ * H_ + (size_t)B_ * S_;
    avail = (avail > head) ? (avail - head) : 0;
    int schunks = 32;
    while (schunks > 1 && (size_t)schunks * B_ * K_ > avail) schunks >>= 1;
    int L = S_ / schunks;

    qproj_kernel<<<(B_ * H_) / 4, 256, 0, stream>>>(query, Wq, qws);
    scores_kernel<<<(B_ * S_) / 4, 256, 0, stream>>>(proj_key, qws, w_energy, scores);
    softmax_kernel<<<B_, 256, 0, stream>>>(scores, mask, alphas);
    dim3 g4(schunks, K_ / 1024, B_);
    context_partial_kernel<<<g4, 256, (size_t)L * sizeof(float), stream>>>(value, alphas, partial,
                                                                           schunks, L);
    context_reduce_kernel<<<(B_ * K_) / 256, 256, 0, stream>>>(partial, ctx, schunks);
}

// Round 2
// 785.840 us; speedup vs baseline: 1.0606x; 1.0606x over previous
//
#include <hip/hip_runtime.h>
#include <math.h>

#define B_ 16
#define S_ 4096
#define H_ 1024
#define Q_ 1024
#define K_ 2048

__device__ __forceinline__ float fast_tanh(float x) {
    // tanh(x) = 1 - 2/(exp(2x)+1); exact at both saturations
    float e = __expf(2.0f * x);
    float r = __builtin_amdgcn_rcpf(e + 1.0f);   // v_rcp_f32, ~1 ulp
    return 1.0f - 2.0f * r;
}

__device__ __forceinline__ float wave_reduce_sum(float v) {
#pragma unroll
    for (int off = 32; off > 0; off >>= 1)
        v += __shfl_xor(v, off, 64);
    return v;
}

// ---------------- kernel 1: q[b,h] = sum_q query[b,q] * Wq[h,q] ----------------
__global__ __launch_bounds__(256) void qproj_kernel(const float* __restrict__ query,
                                                    const float* __restrict__ Wq,
                                                    float* __restrict__ qws) {
    int wave = (blockIdx.x * 256 + threadIdx.x) >> 6;
    int lane = threadIdx.x & 63;
    int b = wave >> 10;          // H_=1024
    int h = wave & 1023;
    const float4* wrow = (const float4*)(Wq + (size_t)h * Q_);
    const float4* qrow = (const float4*)(query + (size_t)b * Q_);
    float acc = 0.f;
#pragma unroll
    for (int m = 0; m < 4; ++m) {
        int i = m * 64 + lane;
        float4 w = wrow[i];
        float4 q = qrow[i];
        acc += w.x * q.x + w.y * q.y + w.z * q.z + w.w * q.w;
    }
    acc = wave_reduce_sum(acc);
    if (lane == 0) qws[wave] = acc;
}

// ---------------- kernel 2: scores[b,s] = sum_h tanh(q[b,h]+pk[b,s,h]) * we[h] ----------------
// one wave per (b,s) row; masked rows exit before touching proj_key (halves pk traffic)
__global__ __launch_bounds__(256) void scores_kernel(const float* __restrict__ pk,
                                                     const float* __restrict__ qws,
                                                     const float* __restrict__ we,
                                                     const int* __restrict__ mask,
                                                     float* __restrict__ scores) {
    int row  = (blockIdx.x * 256 + threadIdx.x) >> 6;  // b*S_ + s
    int lane = threadIdx.x & 63;
    if (mask[row] == 0) return;       // wave-uniform: whole wave owns one row
    int b = row >> 12;                // S_=4096
    const float4* prow = (const float4*)(pk + (size_t)row * H_);
    const float4* qrow = (const float4*)(qws + (size_t)b * H_);
    const float4* wrow = (const float4*)we;
    float acc = 0.f;
#pragma unroll
    for (int m = 0; m < 4; ++m) {
        int i = m * 64 + lane;
        float4 p = prow[i];
        float4 q = qrow[i];
        float4 w = wrow[i];
        acc += fast_tanh(q.x + p.x) * w.x;
        acc += fast_tanh(q.y + p.y) * w.y;
        acc += fast_tanh(q.z + p.z) * w.z;
        acc += fast_tanh(q.w + p.w) * w.w;
    }
    acc = wave_reduce_sum(acc);
    if (lane == 0) scores[row] = acc;
}

// ---------------- kernel 3: masked softmax + ordered compaction; one block per b ----------------
// thread t owns contiguous s in [t*16, t*16+16)
__global__ __launch_bounds__(256) void softmax_kernel(const float* __restrict__ scores,
                                                      const int* __restrict__ mask,
                                                      float* __restrict__ alphas,
                                                      int* __restrict__ cidx,
                                                      float* __restrict__ calpha,
                                                      int* __restrict__ count) {
    int b = blockIdx.x;
    int tid = threadIdx.x;
    __shared__ float red[8];
    __shared__ int scan[256];
    float v[16];
    int mk[16];
    int base = b * S_ + tid * 16;
    float lmax = -INFINITY;
    int myc = 0;
#pragma unroll
    for (int m = 0; m < 16; ++m) {
        float sc = scores[base + m];
        int mm = mask[base + m];
        mk[m] = mm;
        v[m] = mm ? sc : -INFINITY;
        lmax = fmaxf(lmax, v[m]);
        myc += (mm != 0);
    }
#pragma unroll
    for (int off = 32; off > 0; off >>= 1)
        lmax = fmaxf(lmax, __shfl_xor(lmax, off, 64));
    int wid = tid >> 6;
    if ((tid & 63) == 0) red[wid] = lmax;
    __syncthreads();
    float mx = fmaxf(fmaxf(red[0], red[1]), fmaxf(red[2], red[3]));
    float lsum = 0.f;
#pragma unroll
    for (int m = 0; m < 16; ++m) {
        float e = mk[m] ? __expf(v[m] - mx) : 0.f;
        v[m] = e;
        lsum += e;
    }
    lsum = wave_reduce_sum(lsum);
    if ((tid & 63) == 0) red[4 + wid] = lsum;
    __syncthreads();
    float total = red[4] + red[5] + red[6] + red[7];
    float rinv = 1.0f / total;
    // block-wide inclusive scan of per-thread active counts (Hillis-Steele in LDS)
    scan[tid] = myc;
    __syncthreads();
    for (int off = 1; off < 256; off <<= 1) {
        int t = (tid >= off) ? scan[tid - off] : 0;
        __syncthreads();
        scan[tid] += t;
        __syncthreads();
    }
    int pos = scan[tid] - myc;   // exclusive prefix
    if (tid == 255) count[b] = scan[255];
#pragma unroll
    for (int m = 0; m < 16; ++m) {
        float a = v[m] * rinv;
        alphas[base + m] = a;    // exact 0 at masked positions, matches reference
        if (mk[m]) {
            cidx[b * S_ + pos]   = tid * 16 + m;
            calpha[b * S_ + pos] = a;
            pos++;
        }
    }
}

// ---------------- kernel 4: partial context over compacted active rows ----------------
// grid (schunks, K_/1024, B_); block 256; thread owns a float4 of k
__global__ __launch_bounds__(256) void context_partial_kernel(const float* __restrict__ value,
                                                              const float* __restrict__ calpha,
                                                              const int* __restrict__ cidx,
                                                              const int* __restrict__ count,
                                                              float* __restrict__ partial,
                                                              int schunks, int Lmax) {
    extern __shared__ float sh[];
    float* la = sh;
    int*   li = (int*)(sh + Lmax);
    int c  = blockIdx.x;
    int kt = blockIdx.y;
    int b  = blockIdx.z;
    int tid = threadIdx.x;
    int cnt = count[b];
    int L = (cnt + schunks - 1) / schunks;
    int j0 = c * L;
    int j1 = j0 + L; if (j1 > cnt) j1 = cnt;
    int n = j1 - j0; if (n < 0) n = 0;
    for (int i = tid; i < n; i += 256) {
        la[i] = calpha[b * S_ + j0 + i];
        li[i] = cidx[b * S_ + j0 + i];
    }
    __syncthreads();
    const float* vbase = value + (size_t)b * S_ * K_ + kt * 1024;
    float4 acc = make_float4(0.f, 0.f, 0.f, 0.f);
#pragma unroll 4
    for (int i = 0; i < n; ++i) {
        float a = la[i];
        int   s = li[i];
        float4 vv = *((const float4*)(vbase + (size_t)s * K_) + tid);
        acc.x = fmaf(a, vv.x, acc.x);
        acc.y = fmaf(a, vv.y, acc.y);
        acc.z = fmaf(a, vv.z, acc.z);
        acc.w = fmaf(a, vv.w, acc.w);
    }
    float4* pout = (float4*)(partial + ((size_t)(b * schunks + c)) * K_ + kt * 1024) + tid;
    *pout = acc;   // unconditional: partial buffer is poisoned, must be defined
}

// ---------------- kernel 5: reduce partials into context ----------------
__global__ __launch_bounds__(256) void context_reduce_kernel(const float* __restrict__ partial,
                                                             float* __restrict__ ctx,
                                                             int schunks) {
    int idx = blockIdx.x * 256 + threadIdx.x;
    int b = idx >> 11;                         // K_=2048
    int k = idx & 2047;
    float acc = 0.f;
    for (int c = 0; c < schunks; ++c)
        acc += partial[((size_t)(b * schunks + c)) * K_ + k];
    ctx[idx] = acc;
}

extern "C" void kernel_launch(void* const* d_in, const int* in_sizes, int n_in,
                              void* d_out, int out_size, void* d_ws, size_t ws_size,
                              hipStream_t stream) {
    const int*   mask     = (const int*)d_in[0];
    const float* query    = (const float*)d_in[1];
    const float* proj_key = (const float*)d_in[2];
    const float* value    = (const float*)d_in[3];
    const float* Wq       = (const float*)d_in[4];
    const float* w_energy = (const float*)d_in[5];

    float* out    = (float*)d_out;
    float* ctx    = out;            // B*1*K
    float* alphas = out + B_ * K_;  // B*1*S

    float* ws      = (float*)d_ws;
    float* qws     = ws;                                   // B*H
    float* scores  = qws + B_ * H_;                        // B*S
    float* calpha  = scores + B_ * S_;                     // B*S
    int*   cidx    = (int*)(calpha + B_ * S_);             // B*S
    int*   count   = cidx + B_ * S_;                       // B
    float* partial = (float*)(count + 64);                 // schunks*B*K

    size_t used_head = (size_t)(B_ * H_ + 3 * B_ * S_ + 64);
    size_t avail = ws_size / 4;
    avail = (avail > used_head) ? (avail - used_head) : 0;
    int schunks = 32;
    while (schunks > 1 && (size_t)schunks * B_ * K_ > avail) schunks >>= 1;
    int Lmax = (S_ + schunks - 1) / schunks;

    qproj_kernel<<<(B_ * H_) / 4, 256, 0, stream>>>(query, Wq, qws);
    scores_kernel<<<(B_ * S_) / 4, 256, 0, stream>>>(proj_key, qws, w_energy, mask, scores);
    softmax_kernel<<<B_, 256, 0, stream>>>(scores, mask, alphas, cidx, calpha, count);
    dim3 g4(schunks, K_ / 1024, B_);
    size_t shbytes = (size_t)Lmax * (sizeof(float) + sizeof(int));
    context_partial_kernel<<<g4, 256, shbytes, stream>>>(value, calpha, cidx, count, partial,
                                                         schunks, Lmax);
    context_reduce_kernel<<<(B_ * K_) / 256, 256, 0, stream>>>(partial, ctx, schunks);
}